// Round 18
// baseline (74.621 us; speedup 1.0000x reference)
//
#include <hip/hip_runtime.h>
#include <hip/hip_fp16.h>

// Round 18: restore r11 (verified best 65.5us; r16/r17 experiments reverted —
// r17's grid-barrier fusion hit cross-XCD L2 staleness, G16) + one safe change
// in k_scores: balanced hq/hk MFMA split. Each wave computes only the aux
// MFMAs whose results it publishes (wr==wc -> hqA 4 MFMA; wr!=wc -> hkA 2),
// instead of all 6 redundantly. Barrier-locked per-step critical path 14->12
// MFMA + one less ds_read/wave. Coverage exact; results bit-identical.

#define DEVI __device__ __forceinline__

typedef _Float16 half8 __attribute__((ext_vector_type(8)));
typedef _Float16 half4v __attribute__((ext_vector_type(4)));
typedef float f32x4 __attribute__((ext_vector_type(4)));

DEVI void gload16(const void* g, void* l) {
  __builtin_amdgcn_global_load_lds(
      (const __attribute__((address_space(1))) void*)g,
      (__attribute__((address_space(3))) void*)l, 16, 0, 0);
}

DEVI half8 cvt8(float4 a, float4 b) {
  half8 h;
  h[0] = (_Float16)a.x; h[1] = (_Float16)a.y; h[2] = (_Float16)a.z; h[3] = (_Float16)a.w;
  h[4] = (_Float16)b.x; h[5] = (_Float16)b.y; h[6] = (_Float16)b.z; h[7] = (_Float16)b.w;
  return h;
}

#define MEMBAR asm volatile("" ::: "memory")
#define LGKM0  asm volatile("s_waitcnt lgkmcnt(0)" ::: "memory")
#define SBAR   __builtin_amdgcn_s_barrier()
#define VMW(n) asm volatile("s_waitcnt vmcnt(" #n ")" ::: "memory")

// ---------------------------------------------------------------------------
// K1: [Q|K|V] = x * W^T with in-register fp32->fp16 conversion. (r11 verbatim)
__global__ __launch_bounds__(256) void k_qkv(
    const float* __restrict__ x, const float* __restrict__ Wq,
    const float* __restrict__ Wk, const float* __restrict__ Wv,
    _Float16* __restrict__ Qh, _Float16* __restrict__ Kh, _Float16* __restrict__ Vt)
{
  __shared__ _Float16 As[2 * 128 * 32], Bs[2 * 64 * 32];
  const int bid0 = blockIdx.x;
  const int bid = (bid0 & 7) * 96 + (bid0 >> 3);   // XCD chunking
  const int mt = bid / 24, ntg = bid - mt * 24;
  const int mat = ntg >> 3, ntl = ntg & 7;          // 0:Q 1:K 2:V
  const float* W = (mat == 0) ? Wq : ((mat == 1) ? Wk : Wv);
  const float* Ag = x + (size_t)mt * 128 * 512;
  const float* Bg = W + (size_t)ntl * 64 * 512;

  const int tid = threadIdx.x;
  const int l = tid & 63, w = tid >> 6, wr = w >> 1, wc = w & 1;
  const int frow = l & 15, kof = (l >> 4) * 8;
  const int ar = tid >> 1, ac = (tid & 1) * 16;
  const int br = tid >> 2, bc = (tid & 3) * 8;

  f32x4 acc[4][2] = {};
  float4 fa0, fa1, fa2, fa3, fb0, fb1;

  auto loadT = [&](int kt) {
    const float4* pa = (const float4*)(Ag + (size_t)ar * 512 + kt + ac);
    fa0 = pa[0]; fa1 = pa[1]; fa2 = pa[2]; fa3 = pa[3];
    const float4* pb = (const float4*)(Bg + (size_t)br * 512 + kt + bc);
    fb0 = pb[0]; fb1 = pb[1];
  };
  auto writeT = [&](int buf) {
    *(half8*)(As + buf * 4096 + ar * 32 + ac)     = cvt8(fa0, fa1);
    *(half8*)(As + buf * 4096 + ar * 32 + ac + 8) = cvt8(fa2, fa3);
    *(half8*)(Bs + buf * 2048 + br * 32 + bc)     = cvt8(fb0, fb1);
  };
  auto compute = [&](int buf) {
    half8 aF[4], bF[2];
#pragma unroll
    for (int mf = 0; mf < 4; ++mf)
      aF[mf] = *(const half8*)(As + buf * 4096 + (wr * 64 + mf * 16 + frow) * 32 + kof);
#pragma unroll
    for (int nf = 0; nf < 2; ++nf)
      bF[nf] = *(const half8*)(Bs + buf * 2048 + (wc * 32 + nf * 16 + frow) * 32 + kof);
#pragma unroll
    for (int mf = 0; mf < 4; ++mf)
#pragma unroll
      for (int nf = 0; nf < 2; ++nf)
        acc[mf][nf] = __builtin_amdgcn_mfma_f32_16x16x32_f16(aF[mf], bF[nf], acc[mf][nf], 0, 0, 0);
  };

  loadT(0); writeT(0);
  __syncthreads();
  int cur = 0;
  for (int kt = 32; kt < 512; kt += 32) {
    loadT(kt);
    compute(cur);
    writeT(cur ^ 1);
    __syncthreads();
    cur ^= 1;
  }
  compute(cur);

  const int nc0 = ntl * 64 + wc * 32 + frow;
  const int mr0 = mt * 128 + wr * 64 + (l >> 4) * 4;
#pragma unroll
  for (int mf = 0; mf < 4; ++mf)
#pragma unroll
    for (int nf = 0; nf < 2; ++nf) {
      const int col = nc0 + nf * 16;
      if (mat == 0) {
#pragma unroll
        for (int r = 0; r < 4; ++r)
          Qh[(size_t)(mr0 + mf * 16 + r) * 512 + col] = (_Float16)acc[mf][nf][r];
      } else if (mat == 1) {
#pragma unroll
        for (int r = 0; r < 4; ++r)
          Kh[(size_t)(mr0 + mf * 16 + r) * 512 + col] = (_Float16)acc[mf][nf][r];
      } else {
        const int row0 = mr0 + mf * 16;
        const int bb = row0 >> 10, s0 = row0 & 1023;
        half4v hv;
#pragma unroll
        for (int r = 0; r < 4; ++r) hv[r] = (_Float16)acc[mf][nf][r];
        *(half4v*)(Vt + ((size_t)bb * 512 + col) * 1024 + s0) = hv;
      }
    }
}

// ---------------------------------------------------------------------------
// K2: fused scores + hq/hk (balanced wave split) + est + exp(s-6).
// 128(q)x64(k), grid (16,8,4). 3-deep counted-vmcnt pipeline.
__global__ __launch_bounds__(256) void k_scores(
    const _Float16* __restrict__ Qh, const _Float16* __restrict__ Kh,
    const float* __restrict__ W1, const float* __restrict__ b1,
    const float* __restrict__ W2,
    _Float16* __restrict__ P, float* __restrict__ partials)
{
  __shared__ _Float16 As[3 * 128 * 32];   // 24KB; aliased post-loop by Eqs/Eks
  __shared__ _Float16 Bs[3 * 64 * 32];    // 12KB; aliased post-loop by sums
  __shared__ _Float16 W1fq[16 * 512], W1fk[16 * 512];   // 32KB [step][lane*8+j]
  __shared__ float w2s[16];
  float* Eqs = (float*)As;                // 128*17*4 = 8704B
  float* Eks = ((float*)As) + 128 * 17;   // 64*17*4  = 4352B
  float* sums = (float*)Bs;               // [2][128] = 1KB

  const int kt = blockIdx.x, qt = blockIdx.y, b = blockIdx.z;
  const int tid = threadIdx.x;
  const int l = tid & 63, w = tid >> 6, wr = w >> 1, wc = w & 1;
  const int frow = l & 15, kof = (l >> 4) * 8;
  if (tid < 16) w2s[tid] = W2[tid];

  // One-time W1 -> LDS, frag-major: W1fq[t*512 + lane*8 + j] (conflict-free)
#pragma unroll
  for (int c = tid; c < 1024; c += 256) {
    const int t = c >> 6, lj = c & 63;
    const int e0 = t * 32 + (lj >> 4) * 8;
    const float4* pq = (const float4*)(W1 + (lj & 15) * 1024 + e0);
    *(half8*)(W1fq + c * 8) = cvt8(pq[0], pq[1]);
    const float4* pk = (const float4*)(W1 + (lj & 15) * 1024 + 512 + e0);
    *(half8*)(W1fk + c * 8) = cvt8(pk[0], pk[1]);
  }

  const _Float16* Ag = Qh + (size_t)(b * 1024 + qt * 128) * 512;
  const _Float16* Bg = Kh + (size_t)(b * 1024 + kt * 64) * 512;
  const int srA = tid >> 2, scA = (tid & 3) * 8;

  f32x4 acc[4][2] = {};
  f32x4 hqA[4] = {};
  f32x4 hkA[2] = {};
  const bool doHq = (wr == wc);          // wave-uniform role split

  auto stage = [&](int buf, int k2) {   // exactly 3 vmem ops
    gload16(Ag + (size_t)srA * 512 + k2 + scA,        As + buf * 4096 + tid * 8);
    gload16(Ag + (size_t)(srA + 64) * 512 + k2 + scA, As + buf * 4096 + (tid + 256) * 8);
    gload16(Bg + (size_t)srA * 512 + k2 + scA,        Bs + buf * 2048 + tid * 8);
  };
  auto compute = [&](int buf, int tstep) {
    half8 aF[4], bF[2];
#pragma unroll
    for (int mf = 0; mf < 4; ++mf)
      aF[mf] = *(const half8*)(As + buf * 4096 + (wr * 64 + mf * 16 + frow) * 32 + kof);
#pragma unroll
    for (int nf = 0; nf < 2; ++nf)
      bF[nf] = *(const half8*)(Bs + buf * 2048 + (wc * 32 + nf * 16 + frow) * 32 + kof);
#pragma unroll
    for (int mf = 0; mf < 4; ++mf)
#pragma unroll
      for (int nf = 0; nf < 2; ++nf)
        acc[mf][nf] = __builtin_amdgcn_mfma_f32_16x16x32_f16(aF[mf], bF[nf], acc[mf][nf], 0, 0, 0);
    if (doHq) {                           // wave-uniform branch
      const half8 wqF = *(const half8*)(W1fq + tstep * 512 + l * 8);
#pragma unroll
      for (int mf = 0; mf < 4; ++mf)
        hqA[mf] = __builtin_amdgcn_mfma_f32_16x16x32_f16(aF[mf], wqF, hqA[mf], 0, 0, 0);
    } else {
      const half8 wkF = *(const half8*)(W1fk + tstep * 512 + l * 8);
#pragma unroll
      for (int nf = 0; nf < 2; ++nf)
        hkA[nf] = __builtin_amdgcn_mfma_f32_16x16x32_f16(wkF, bF[nf], hkA[nf], 0, 0, 0);
    }
  };

  // 3-deep prologue: tiles 0,1,2 in flight (9 loads)
  stage(0, 0); stage(1, 32); stage(2, 64);
  LGKM0;                                 // W1f + w2s ds_writes drained (per wave)
  for (int t = 0; t < 13; ++t) {
    VMW(6); SBAR; MEMBAR;                // tile t's 3 loads done (6 younger fly)
    compute(t % 3, t);
    MEMBAR; SBAR;                        // all waves done reading buf t%3
    stage(t % 3, 32 * (t + 3));          // refill with tile t+3
  }
  VMW(6); SBAR; MEMBAR; compute(1, 13); MEMBAR; SBAR;
  VMW(3); SBAR; MEMBAR; compute(2, 14); MEMBAR; SBAR;
  VMW(0); SBAR; MEMBAR; compute(0, 15);
  MEMBAR; SBAR;                          // all As reads done before alias writes

  // Ea/Eb -> LDS (aliased onto As).
  //   hqA (waves wr==wc): lane = q-rows wr*64+(l>>4)*4+r, head = frow.
  //   hkA (waves wr!=wc): lane = head (l>>4)*4+r, K-row = frow of wc half.
  const int lr0 = wr * 64 + (l >> 4) * 4;
  if (doHq) {
    const float b1v = b1[frow];
#pragma unroll
    for (int mf = 0; mf < 4; ++mf)
#pragma unroll
      for (int r = 0; r < 4; ++r)
        Eqs[(lr0 + mf * 16 + r) * 17 + frow] = __expf(2.f * (hqA[mf][r] + b1v));
  } else {
#pragma unroll
    for (int nf = 0; nf < 2; ++nf)
#pragma unroll
      for (int r = 0; r < 4; ++r)
        Eks[(wc * 32 + nf * 16 + frow) * 17 + ((l >> 4) * 4 + r)] = __expf(2.f * hkA[nf][r]);
  }
  __syncthreads();

  const float scale = 0.044194173824159216f;  // 1/sqrt(512)
#pragma unroll
  for (int mf = 0; mf < 4; ++mf)
#pragma unroll
    for (int nf = 0; nf < 2; ++nf)
      acc[mf][nf] *= scale;

  // est: acc += w2*(1 - 2/(Ea*Eb+1));  w2-sum folded into bias
  const int lc0 = wc * 32 + frow;
  float w2sum = 0.f;
#pragma unroll
  for (int h = 0; h < 16; ++h) {
    const float w2v = w2s[h];
    const float tw2 = -2.f * w2v;
    w2sum += w2v;
    float Eb[2];
#pragma unroll
    for (int nf = 0; nf < 2; ++nf) Eb[nf] = Eks[(lc0 + nf * 16) * 17 + h];
#pragma unroll
    for (int mf = 0; mf < 4; ++mf)
#pragma unroll
      for (int r = 0; r < 4; ++r) {
        const float Ea = Eqs[(lr0 + mf * 16 + r) * 17 + h];
#pragma unroll
        for (int nf = 0; nf < 2; ++nf) {
          const float t = __builtin_fmaf(Ea, Eb[nf], 1.f);
          const float rc = __builtin_amdgcn_rcpf(t);
          acc[mf][nf][r] = __builtin_fmaf(tw2, rc, acc[mf][nf][r]);
        }
      }
  }

  const float bias = w2sum - 6.f;
#pragma unroll
  for (int mf = 0; mf < 4; ++mf)
#pragma unroll
    for (int nf = 0; nf < 2; ++nf)
#pragma unroll
      for (int r = 0; r < 4; ++r)
        acc[mf][nf][r] = __expf(acc[mf][nf][r] + bias);

  float rp[4][4];
#pragma unroll
  for (int mf = 0; mf < 4; ++mf)
#pragma unroll
    for (int r = 0; r < 4; ++r) {
      float s = acc[mf][0][r] + acc[mf][1][r];
#pragma unroll
      for (int off = 1; off < 16; off <<= 1) s += __shfl_xor(s, off);
      rp[mf][r] = s;
    }

  __syncthreads();                 // Eqs/Eks reads done; sums lives in Bs
  if (frow == 0) {
#pragma unroll
    for (int mf = 0; mf < 4; ++mf)
#pragma unroll
      for (int r = 0; r < 4; ++r)
        sums[wc * 128 + lr0 + mf * 16 + r] = rp[mf][r];
  }
  __syncthreads();
  if (tid < 128)
    partials[((size_t)b * 1024 + qt * 128 + tid) * 16 + kt] = sums[tid] + sums[128 + tid];

  _Float16* Pb = P + ((size_t)b << 20);
#pragma unroll
  for (int mf = 0; mf < 4; ++mf)
#pragma unroll
    for (int nf = 0; nf < 2; ++nf) {
      const int col = kt * 64 + lc0 + nf * 16;
#pragma unroll
      for (int r = 0; r < 4; ++r)
        Pb[(size_t)(qt * 128 + lr0 + mf * 16 + r) * 1024 + col] = (_Float16)acc[mf][nf][r];
    }
}

// ---------------------------------------------------------------------------
// K3: out = (P * Vt) / rowsum. 64x64 tiles, BK=32, 3-deep counted vmcnt.
// (r11 verbatim)
__global__ __launch_bounds__(256) void k_pv(
    const _Float16* __restrict__ P, const _Float16* __restrict__ Vt,
    const float* __restrict__ partials, float* __restrict__ out)
{
  __shared__ _Float16 As[3 * 64 * 32], Bs[3 * 64 * 32];   // 12KB + 12KB
  __shared__ float rinv[64];
  const int nt = blockIdx.x, mt = blockIdx.y, b = blockIdx.z;
  const int tid = threadIdx.x;
  if (tid < 64) {
    const float4* pp = (const float4*)(partials + ((size_t)b * 1024 + mt * 64 + tid) * 16);
    float4 s0 = pp[0], s1 = pp[1], s2 = pp[2], s3 = pp[3];
    rinv[tid] = 1.f / (((s0.x + s0.y + s0.z + s0.w) + (s1.x + s1.y + s1.z + s1.w)) +
                       ((s2.x + s2.y + s2.z + s2.w) + (s3.x + s3.y + s3.z + s3.w)));
  }

  const int l = tid & 63, w = tid >> 6, wr = w >> 1, wc = w & 1;
  const int frow = l & 15, kof = (l >> 4) * 8;
  const int srow = tid >> 2, scol = (tid & 3) * 8;
  const _Float16* Ag = P + ((size_t)b << 20) + (size_t)mt * 64 * 1024 + (size_t)srow * 1024 + scol;
  const _Float16* Bg = Vt + ((size_t)b * 512 + nt * 64) * 1024 + (size_t)srow * 1024 + scol;

  f32x4 acc[2][2] = {};

  auto stage = [&](int buf, int kt2) {   // exactly 2 vmem ops
    gload16(Ag + kt2, As + buf * 2048 + tid * 8);
    gload16(Bg + kt2, Bs + buf * 2048 + tid * 8);
  };
  auto compute = [&](int buf) {
    half8 aF[2], bF[2];
#pragma unroll
    for (int mf = 0; mf < 2; ++mf)
      aF[mf] = *(const half8*)(As + buf * 2048 + (wr * 32 + mf * 16 + frow) * 32 + kof);
#pragma unroll
    for (int nf = 0; nf < 2; ++nf)
      bF[nf] = *(const half8*)(Bs + buf * 2048 + (wc * 32 + nf * 16 + frow) * 32 + kof);
#pragma unroll
    for (int mf = 0; mf < 2; ++mf)
#pragma unroll
      for (int nf = 0; nf < 2; ++nf)
        acc[mf][nf] = __builtin_amdgcn_mfma_f32_16x16x32_f16(aF[mf], bF[nf], acc[mf][nf], 0, 0, 0);
  };

  stage(0, 0); stage(1, 32); stage(2, 64);
  LGKM0;                                 // rinv ds_write drained (per wave)
  for (int t = 0; t < 29; ++t) {
    VMW(4); SBAR; MEMBAR;                // tile t's 2 loads done (4 younger fly)
    compute(t % 3);
    MEMBAR; SBAR;
    stage(t % 3, 32 * (t + 3));
  }
  VMW(4); SBAR; MEMBAR; compute(2); MEMBAR; SBAR;
  VMW(2); SBAR; MEMBAR; compute(0); MEMBAR; SBAR;
  VMW(0); SBAR; MEMBAR; compute(1);

  const int lr0 = wr * 32 + (l >> 4) * 4, lc0 = wc * 32 + frow;
#pragma unroll
  for (int mf = 0; mf < 2; ++mf)
#pragma unroll
    for (int nf = 0; nf < 2; ++nf) {
      const int col = nt * 64 + lc0 + nf * 16;
#pragma unroll
      for (int r = 0; r < 4; ++r) {
        const int lrow = lr0 + mf * 16 + r;
        out[((size_t)(b * 1024 + mt * 64 + lrow)) * 512 + col] = acc[mf][nf][r] * rinv[lrow];
      }
    }
}

// ---------------------------------------------------------------------------
extern "C" void kernel_launch(void* const* d_in, const int* in_sizes, int n_in,
                              void* d_out, int out_size, void* d_ws, size_t ws_size,
                              hipStream_t stream)
{
  const float* x  = (const float*)d_in[0];
  const float* Wq = (const float*)d_in[1];
  const float* Wk = (const float*)d_in[2];
  const float* Wv = (const float*)d_in[3];
  const float* W1 = (const float*)d_in[4];
  const float* b1 = (const float*)d_in[5];
  const float* W2 = (const float*)d_in[6];
  float* out = (float*)d_out;

  char* ws = (char*)d_ws;
  size_t off = 0;
  auto alloc = [&](size_t bytes) { char* p = ws + off; off += (bytes + 255) & ~255ull; return p; };
  _Float16* Qh    = (_Float16*)alloc(4096ull * 512 * 2);
  _Float16* Kh    = (_Float16*)alloc(4096ull * 512 * 2);
  _Float16* Vt    = (_Float16*)alloc(4ull * 512 * 1024 * 2);
  float*  parts   = (float*)alloc(4096ull * 16 * 4);
  _Float16* P     = (_Float16*)alloc(4ull * 1024 * 1024 * 2);

  k_qkv<<<768, 256, 0, stream>>>(x, Wq, Wk, Wv, Qh, Kh, Vt);
  k_scores<<<dim3(16, 8, 4), 256, 0, stream>>>(Qh, Kh, W1, b1, W2, P, parts);
  k_pv<<<dim3(8, 16, 4), 256, 0, stream>>>(P, Vt, parts, out);
}

// Round 19
// 65.303 us; speedup vs baseline: 1.1427x; 1.1427x over previous
//
#include <hip/hip_runtime.h>
#include <hip/hip_fp16.h>

// Round 19: REVERT to r11 verbatim — the verified best (65.5us, absmax 2e-3).
// r18's balanced hq/hk wave-split regressed +9us (branch-in-K-loop defeats
// compiler pipeline scheduling + barrier skew between role-split waves).
// Session summary: 102.6 -> 65.5us via (r2) fused fixed-offset softmax,
// (r4) 5->3 kernels, (r6) W1-frag preload killing vmcnt entanglement (-15),
// (r8) counted-vmcnt double-buffer T4 (-10), (r11) 3-deep pipeline. Remaining
// ~20us is kernel-boundary cost: both removal mechanisms are hard-blocked
// (cooperative launch no-ops under graph capture; manual grid barrier hits
// cross-XCD L2 staleness per G16). Intra-kernel levers tested and neutral.

#define DEVI __device__ __forceinline__

typedef _Float16 half8 __attribute__((ext_vector_type(8)));
typedef _Float16 half4v __attribute__((ext_vector_type(4)));
typedef float f32x4 __attribute__((ext_vector_type(4)));

DEVI void gload16(const void* g, void* l) {
  __builtin_amdgcn_global_load_lds(
      (const __attribute__((address_space(1))) void*)g,
      (__attribute__((address_space(3))) void*)l, 16, 0, 0);
}

DEVI half8 cvt8(float4 a, float4 b) {
  half8 h;
  h[0] = (_Float16)a.x; h[1] = (_Float16)a.y; h[2] = (_Float16)a.z; h[3] = (_Float16)a.w;
  h[4] = (_Float16)b.x; h[5] = (_Float16)b.y; h[6] = (_Float16)b.z; h[7] = (_Float16)b.w;
  return h;
}

#define MEMBAR asm volatile("" ::: "memory")
#define LGKM0  asm volatile("s_waitcnt lgkmcnt(0)" ::: "memory")
#define SBAR   __builtin_amdgcn_s_barrier()
#define VMW(n) asm volatile("s_waitcnt vmcnt(" #n ")" ::: "memory")

// ---------------------------------------------------------------------------
// K1: [Q|K|V] = x * W^T with in-register fp32->fp16 conversion.
__global__ __launch_bounds__(256) void k_qkv(
    const float* __restrict__ x, const float* __restrict__ Wq,
    const float* __restrict__ Wk, const float* __restrict__ Wv,
    _Float16* __restrict__ Qh, _Float16* __restrict__ Kh, _Float16* __restrict__ Vt)
{
  __shared__ _Float16 As[2 * 128 * 32], Bs[2 * 64 * 32];
  const int bid0 = blockIdx.x;
  const int bid = (bid0 & 7) * 96 + (bid0 >> 3);   // XCD chunking
  const int mt = bid / 24, ntg = bid - mt * 24;
  const int mat = ntg >> 3, ntl = ntg & 7;          // 0:Q 1:K 2:V
  const float* W = (mat == 0) ? Wq : ((mat == 1) ? Wk : Wv);
  const float* Ag = x + (size_t)mt * 128 * 512;
  const float* Bg = W + (size_t)ntl * 64 * 512;

  const int tid = threadIdx.x;
  const int l = tid & 63, w = tid >> 6, wr = w >> 1, wc = w & 1;
  const int frow = l & 15, kof = (l >> 4) * 8;
  const int ar = tid >> 1, ac = (tid & 1) * 16;
  const int br = tid >> 2, bc = (tid & 3) * 8;

  f32x4 acc[4][2] = {};
  float4 fa0, fa1, fa2, fa3, fb0, fb1;

  auto loadT = [&](int kt) {
    const float4* pa = (const float4*)(Ag + (size_t)ar * 512 + kt + ac);
    fa0 = pa[0]; fa1 = pa[1]; fa2 = pa[2]; fa3 = pa[3];
    const float4* pb = (const float4*)(Bg + (size_t)br * 512 + kt + bc);
    fb0 = pb[0]; fb1 = pb[1];
  };
  auto writeT = [&](int buf) {
    *(half8*)(As + buf * 4096 + ar * 32 + ac)     = cvt8(fa0, fa1);
    *(half8*)(As + buf * 4096 + ar * 32 + ac + 8) = cvt8(fa2, fa3);
    *(half8*)(Bs + buf * 2048 + br * 32 + bc)     = cvt8(fb0, fb1);
  };
  auto compute = [&](int buf) {
    half8 aF[4], bF[2];
#pragma unroll
    for (int mf = 0; mf < 4; ++mf)
      aF[mf] = *(const half8*)(As + buf * 4096 + (wr * 64 + mf * 16 + frow) * 32 + kof);
#pragma unroll
    for (int nf = 0; nf < 2; ++nf)
      bF[nf] = *(const half8*)(Bs + buf * 2048 + (wc * 32 + nf * 16 + frow) * 32 + kof);
#pragma unroll
    for (int mf = 0; mf < 4; ++mf)
#pragma unroll
      for (int nf = 0; nf < 2; ++nf)
        acc[mf][nf] = __builtin_amdgcn_mfma_f32_16x16x32_f16(aF[mf], bF[nf], acc[mf][nf], 0, 0, 0);
  };

  loadT(0); writeT(0);
  __syncthreads();
  int cur = 0;
  for (int kt = 32; kt < 512; kt += 32) {
    loadT(kt);
    compute(cur);
    writeT(cur ^ 1);
    __syncthreads();
    cur ^= 1;
  }
  compute(cur);

  const int nc0 = ntl * 64 + wc * 32 + frow;
  const int mr0 = mt * 128 + wr * 64 + (l >> 4) * 4;
#pragma unroll
  for (int mf = 0; mf < 4; ++mf)
#pragma unroll
    for (int nf = 0; nf < 2; ++nf) {
      const int col = nc0 + nf * 16;
      if (mat == 0) {
#pragma unroll
        for (int r = 0; r < 4; ++r)
          Qh[(size_t)(mr0 + mf * 16 + r) * 512 + col] = (_Float16)acc[mf][nf][r];
      } else if (mat == 1) {
#pragma unroll
        for (int r = 0; r < 4; ++r)
          Kh[(size_t)(mr0 + mf * 16 + r) * 512 + col] = (_Float16)acc[mf][nf][r];
      } else {
        const int row0 = mr0 + mf * 16;
        const int bb = row0 >> 10, s0 = row0 & 1023;
        half4v hv;
#pragma unroll
        for (int r = 0; r < 4; ++r) hv[r] = (_Float16)acc[mf][nf][r];
        *(half4v*)(Vt + ((size_t)bb * 512 + col) * 1024 + s0) = hv;
      }
    }
}

// ---------------------------------------------------------------------------
// K2: fused scores + hq/hk (W1f LDS preload) + est + exp(s-6).
// 128(q)x64(k), grid (16,8,4). 3-deep counted-vmcnt pipeline.
__global__ __launch_bounds__(256) void k_scores(
    const _Float16* __restrict__ Qh, const _Float16* __restrict__ Kh,
    const float* __restrict__ W1, const float* __restrict__ b1,
    const float* __restrict__ W2,
    _Float16* __restrict__ P, float* __restrict__ partials)
{
  __shared__ _Float16 As[3 * 128 * 32];   // 24KB; aliased post-loop by Eqs/Eks
  __shared__ _Float16 Bs[3 * 64 * 32];    // 12KB; aliased post-loop by sums
  __shared__ _Float16 W1fq[16 * 512], W1fk[16 * 512];   // 32KB [step][lane*8+j]
  __shared__ float w2s[16];
  float* Eqs = (float*)As;                // 128*17*4 = 8704B
  float* Eks = ((float*)As) + 128 * 17;   // 64*17*4  = 4352B
  float* sums = (float*)Bs;               // [2][128] = 1KB

  const int kt = blockIdx.x, qt = blockIdx.y, b = blockIdx.z;
  const int tid = threadIdx.x;
  const int l = tid & 63, w = tid >> 6, wr = w >> 1, wc = w & 1;
  const int frow = l & 15, kof = (l >> 4) * 8;
  if (tid < 16) w2s[tid] = W2[tid];

  // One-time W1 -> LDS, frag-major: W1fq[t*512 + lane*8 + j] (conflict-free)
#pragma unroll
  for (int c = tid; c < 1024; c += 256) {
    const int t = c >> 6, lj = c & 63;
    const int e0 = t * 32 + (lj >> 4) * 8;
    const float4* pq = (const float4*)(W1 + (lj & 15) * 1024 + e0);
    *(half8*)(W1fq + c * 8) = cvt8(pq[0], pq[1]);
    const float4* pk = (const float4*)(W1 + (lj & 15) * 1024 + 512 + e0);
    *(half8*)(W1fk + c * 8) = cvt8(pk[0], pk[1]);
  }

  const _Float16* Ag = Qh + (size_t)(b * 1024 + qt * 128) * 512;
  const _Float16* Bg = Kh + (size_t)(b * 1024 + kt * 64) * 512;
  const int srA = tid >> 2, scA = (tid & 3) * 8;

  f32x4 acc[4][2] = {};
  f32x4 hqA[4] = {};
  f32x4 hkA[2] = {};

  auto stage = [&](int buf, int k2) {   // exactly 3 vmem ops
    gload16(Ag + (size_t)srA * 512 + k2 + scA,        As + buf * 4096 + tid * 8);
    gload16(Ag + (size_t)(srA + 64) * 512 + k2 + scA, As + buf * 4096 + (tid + 256) * 8);
    gload16(Bg + (size_t)srA * 512 + k2 + scA,        Bs + buf * 2048 + tid * 8);
  };
  auto compute = [&](int buf, int tstep) {
    half8 aF[4], bF[2];
#pragma unroll
    for (int mf = 0; mf < 4; ++mf)
      aF[mf] = *(const half8*)(As + buf * 4096 + (wr * 64 + mf * 16 + frow) * 32 + kof);
#pragma unroll
    for (int nf = 0; nf < 2; ++nf)
      bF[nf] = *(const half8*)(Bs + buf * 2048 + (wc * 32 + nf * 16 + frow) * 32 + kof);
    const half8 wqF = *(const half8*)(W1fq + tstep * 512 + l * 8);
    const half8 wkF = *(const half8*)(W1fk + tstep * 512 + l * 8);
#pragma unroll
    for (int mf = 0; mf < 4; ++mf)
#pragma unroll
      for (int nf = 0; nf < 2; ++nf)
        acc[mf][nf] = __builtin_amdgcn_mfma_f32_16x16x32_f16(aF[mf], bF[nf], acc[mf][nf], 0, 0, 0);
#pragma unroll
    for (int mf = 0; mf < 4; ++mf)
      hqA[mf] = __builtin_amdgcn_mfma_f32_16x16x32_f16(aF[mf], wqF, hqA[mf], 0, 0, 0);
#pragma unroll
    for (int nf = 0; nf < 2; ++nf)
      hkA[nf] = __builtin_amdgcn_mfma_f32_16x16x32_f16(wkF, bF[nf], hkA[nf], 0, 0, 0);
  };

  // 3-deep prologue: tiles 0,1,2 in flight (9 loads)
  stage(0, 0); stage(1, 32); stage(2, 64);
  LGKM0;                                 // W1f + w2s ds_writes drained (per wave)
  for (int t = 0; t < 13; ++t) {
    VMW(6); SBAR; MEMBAR;                // tile t's 3 loads done (6 younger fly)
    compute(t % 3, t);
    MEMBAR; SBAR;                        // all waves done reading buf t%3
    stage(t % 3, 32 * (t + 3));          // refill with tile t+3
  }
  VMW(6); SBAR; MEMBAR; compute(1, 13); MEMBAR; SBAR;
  VMW(3); SBAR; MEMBAR; compute(2, 14); MEMBAR; SBAR;
  VMW(0); SBAR; MEMBAR; compute(0, 15);
  MEMBAR; SBAR;                          // all As reads done before alias writes

  // Ea/Eb -> LDS (aliased onto As).
  //   hqA: lane = q-rows (l>>4)*4+r, head = frow.
  //   hkA: lane = head (l>>4)*4+r, K-row = frow (of wc half).
  const int lr0 = wr * 64 + (l >> 4) * 4;
  if (wc == 0) {
    const float b1v = b1[frow];
#pragma unroll
    for (int mf = 0; mf < 4; ++mf)
#pragma unroll
      for (int r = 0; r < 4; ++r)
        Eqs[(lr0 + mf * 16 + r) * 17 + frow] = __expf(2.f * (hqA[mf][r] + b1v));
  }
  if (wr == 0) {
#pragma unroll
    for (int nf = 0; nf < 2; ++nf)
#pragma unroll
      for (int r = 0; r < 4; ++r)
        Eks[(wc * 32 + nf * 16 + frow) * 17 + ((l >> 4) * 4 + r)] = __expf(2.f * hkA[nf][r]);
  }
  __syncthreads();

  const float scale = 0.044194173824159216f;  // 1/sqrt(512)
#pragma unroll
  for (int mf = 0; mf < 4; ++mf)
#pragma unroll
    for (int nf = 0; nf < 2; ++nf)
      acc[mf][nf] *= scale;

  // est: acc += w2*(1 - 2/(Ea*Eb+1));  w2-sum folded into bias
  const int lc0 = wc * 32 + frow;
  float w2sum = 0.f;
#pragma unroll
  for (int h = 0; h < 16; ++h) {
    const float w2v = w2s[h];
    const float tw2 = -2.f * w2v;
    w2sum += w2v;
    float Eb[2];
#pragma unroll
    for (int nf = 0; nf < 2; ++nf) Eb[nf] = Eks[(lc0 + nf * 16) * 17 + h];
#pragma unroll
    for (int mf = 0; mf < 4; ++mf)
#pragma unroll
      for (int r = 0; r < 4; ++r) {
        const float Ea = Eqs[(lr0 + mf * 16 + r) * 17 + h];
#pragma unroll
        for (int nf = 0; nf < 2; ++nf) {
          const float t = __builtin_fmaf(Ea, Eb[nf], 1.f);
          const float rc = __builtin_amdgcn_rcpf(t);
          acc[mf][nf][r] = __builtin_fmaf(tw2, rc, acc[mf][nf][r]);
        }
      }
  }

  const float bias = w2sum - 6.f;
#pragma unroll
  for (int mf = 0; mf < 4; ++mf)
#pragma unroll
    for (int nf = 0; nf < 2; ++nf)
#pragma unroll
      for (int r = 0; r < 4; ++r)
        acc[mf][nf][r] = __expf(acc[mf][nf][r] + bias);

  float rp[4][4];
#pragma unroll
  for (int mf = 0; mf < 4; ++mf)
#pragma unroll
    for (int r = 0; r < 4; ++r) {
      float s = acc[mf][0][r] + acc[mf][1][r];
#pragma unroll
      for (int off = 1; off < 16; off <<= 1) s += __shfl_xor(s, off);
      rp[mf][r] = s;
    }

  __syncthreads();                 // Eqs/Eks reads done; sums lives in Bs
  if (frow == 0) {
#pragma unroll
    for (int mf = 0; mf < 4; ++mf)
#pragma unroll
      for (int r = 0; r < 4; ++r)
        sums[wc * 128 + lr0 + mf * 16 + r] = rp[mf][r];
  }
  __syncthreads();
  if (tid < 128)
    partials[((size_t)b * 1024 + qt * 128 + tid) * 16 + kt] = sums[tid] + sums[128 + tid];

  _Float16* Pb = P + ((size_t)b << 20);
#pragma unroll
  for (int mf = 0; mf < 4; ++mf)
#pragma unroll
    for (int nf = 0; nf < 2; ++nf) {
      const int col = kt * 64 + lc0 + nf * 16;
#pragma unroll
      for (int r = 0; r < 4; ++r)
        Pb[(size_t)(qt * 128 + lr0 + mf * 16 + r) * 1024 + col] = (_Float16)acc[mf][nf][r];
    }
}

// ---------------------------------------------------------------------------
// K3: out = (P * Vt) / rowsum. 64x64 tiles, BK=32, 3-deep counted vmcnt.
__global__ __launch_bounds__(256) void k_pv(
    const _Float16* __restrict__ P, const _Float16* __restrict__ Vt,
    const float* __restrict__ partials, float* __restrict__ out)
{
  __shared__ _Float16 As[3 * 64 * 32], Bs[3 * 64 * 32];   // 12KB + 12KB
  __shared__ float rinv[64];
  const int nt = blockIdx.x, mt = blockIdx.y, b = blockIdx.z;
  const int tid = threadIdx.x;
  if (tid < 64) {
    const float4* pp = (const float4*)(partials + ((size_t)b * 1024 + mt * 64 + tid) * 16);
    float4 s0 = pp[0], s1 = pp[1], s2 = pp[2], s3 = pp[3];
    rinv[tid] = 1.f / (((s0.x + s0.y + s0.z + s0.w) + (s1.x + s1.y + s1.z + s1.w)) +
                       ((s2.x + s2.y + s2.z + s2.w) + (s3.x + s3.y + s3.z + s3.w)));
  }

  const int l = tid & 63, w = tid >> 6, wr = w >> 1, wc = w & 1;
  const int frow = l & 15, kof = (l >> 4) * 8;
  const int srow = tid >> 2, scol = (tid & 3) * 8;
  const _Float16* Ag = P + ((size_t)b << 20) + (size_t)mt * 64 * 1024 + (size_t)srow * 1024 + scol;
  const _Float16* Bg = Vt + ((size_t)b * 512 + nt * 64) * 1024 + (size_t)srow * 1024 + scol;

  f32x4 acc[2][2] = {};

  auto stage = [&](int buf, int kt2) {   // exactly 2 vmem ops
    gload16(Ag + kt2, As + buf * 2048 + tid * 8);
    gload16(Bg + kt2, Bs + buf * 2048 + tid * 8);
  };
  auto compute = [&](int buf) {
    half8 aF[2], bF[2];
#pragma unroll
    for (int mf = 0; mf < 2; ++mf)
      aF[mf] = *(const half8*)(As + buf * 2048 + (wr * 32 + mf * 16 + frow) * 32 + kof);
#pragma unroll
    for (int nf = 0; nf < 2; ++nf)
      bF[nf] = *(const half8*)(Bs + buf * 2048 + (wc * 32 + nf * 16 + frow) * 32 + kof);
#pragma unroll
    for (int mf = 0; mf < 2; ++mf)
#pragma unroll
      for (int nf = 0; nf < 2; ++nf)
        acc[mf][nf] = __builtin_amdgcn_mfma_f32_16x16x32_f16(aF[mf], bF[nf], acc[mf][nf], 0, 0, 0);
  };

  stage(0, 0); stage(1, 32); stage(2, 64);
  LGKM0;                                 // rinv ds_write drained (per wave)
  for (int t = 0; t < 29; ++t) {
    VMW(4); SBAR; MEMBAR;                // tile t's 2 loads done (4 younger fly)
    compute(t % 3);
    MEMBAR; SBAR;
    stage(t % 3, 32 * (t + 3));
  }
  VMW(4); SBAR; MEMBAR; compute(2); MEMBAR; SBAR;
  VMW(2); SBAR; MEMBAR; compute(0); MEMBAR; SBAR;
  VMW(0); SBAR; MEMBAR; compute(1);

  const int lr0 = wr * 32 + (l >> 4) * 4, lc0 = wc * 32 + frow;
#pragma unroll
  for (int mf = 0; mf < 2; ++mf)
#pragma unroll
    for (int nf = 0; nf < 2; ++nf) {
      const int col = nt * 64 + lc0 + nf * 16;
#pragma unroll
      for (int r = 0; r < 4; ++r) {
        const int lrow = lr0 + mf * 16 + r;
        out[((size_t)(b * 1024 + mt * 64 + lrow)) * 512 + col] = acc[mf][nf][r] * rinv[lrow];
      }
    }
}

// ---------------------------------------------------------------------------
extern "C" void kernel_launch(void* const* d_in, const int* in_sizes, int n_in,
                              void* d_out, int out_size, void* d_ws, size_t ws_size,
                              hipStream_t stream)
{
  const float* x  = (const float*)d_in[0];
  const float* Wq = (const float*)d_in[1];
  const float* Wk = (const float*)d_in[2];
  const float* Wv = (const float*)d_in[3];
  const float* W1 = (const float*)d_in[4];
  const float* b1 = (const float*)d_in[5];
  const float* W2 = (const float*)d_in[6];
  float* out = (float*)d_out;

  char* ws = (char*)d_ws;
  size_t off = 0;
  auto alloc = [&](size_t bytes) { char* p = ws + off; off += (bytes + 255) & ~255ull; return p; };
  _Float16* Qh    = (_Float16*)alloc(4096ull * 512 * 2);
  _Float16* Kh    = (_Float16*)alloc(4096ull * 512 * 2);
  _Float16* Vt    = (_Float16*)alloc(4ull * 512 * 1024 * 2);
  float*  parts   = (float*)alloc(4096ull * 16 * 4);
  _Float16* P     = (_Float16*)alloc(4ull * 1024 * 1024 * 2);

  k_qkv<<<768, 256, 0, stream>>>(x, Wq, Wk, Wv, Qh, Kh, Vt);
  k_scores<<<dim3(16, 8, 4), 256, 0, stream>>>(Qh, Kh, W1, b1, W2, P, parts);
  k_pv<<<dim3(8, 16, 4), 256, 0, stream>>>(P, Vt, parts, out);
}